// Round 2
// baseline (226.237 us; speedup 1.0000x reference)
//
#include <hip/hip_runtime.h>

// DeQuantizer: 4-bit GPTQ-style weight dequantization.
// qweight: int32 [K/8, N], qzeros: int32 [G, N/8], scales: f32 [G, N],
// g_idx: int32 [K] (sorted). out: f32 [K, N].
// out[k][n] = scales[g][n] * (((qw[k/8][n] >> 4*(k%8)) & 15) - ((qz[g][n/8] >> 4*(n%8)) & 15))
// with g = g_idx[k].
//
// Structure (this round): ADDRESS-MAJOR store sweep. Work unit = 256
// consecutive floats of the linear output (N=11008 = 43 units/row, no unit
// straddles a row). One wave produces one unit as a single contiguous 1 KB
// store train. 2048 blocks x 4 waves grid-stride the 176128 units in linear
// order, so the resident grid writes a dense ~8 MB window that sweeps `out`
// monotonically (same profile as the 6.3-6.6 TB/s fill/copy benches), instead
// of the previous 8-row x 44KB-stride scatter (~2.3 TB/s, DRAM page thrash).
// Cost: qweight is re-read once per row (8x) -- these re-reads are L2/L3-hot,
// so loads are plain (cacheable), NOT nontemporal. Per-output VALU unchanged.
// All control flow is wave-uniform (trip count 21 or 22): no predication.

#define NN 11008
#define NPACK 1376               // NN / 8
#define KK 4096
#define UNITS_PER_ROW 43         // NN / 256
#define NUNITS (KK * UNITS_PER_ROW)   // 176128
#define NBLOCKS 2048
#define STRIDE_UNITS (NBLOCKS * 4)    // 8192 units per grid iteration
// NUNITS = 21*STRIDE_UNITS + 4096: waves with pw0 < 4096 run 22 iters, else 21.

typedef int   iv4 __attribute__((ext_vector_type(4)));
typedef float fv4 __attribute__((ext_vector_type(4)));

__global__ __launch_bounds__(256, 8) void dequant_kernel(
    const int* __restrict__ qweight,   // [512, NN]
    const int* __restrict__ qzeros,    // [32, 1376]
    const float* __restrict__ scales,  // [32, NN]
    const int* __restrict__ g_idx,     // [KK]
    float* __restrict__ out)           // [KK, NN]
{
    const int lane4 = (threadIdx.x & 63) * 4;   // this lane's 4 columns within the unit
    // wave-uniform unit base (forced scalar so /43, g_idx go through SALU + s_load)
    const int pw0 = __builtin_amdgcn_readfirstlane(
                        (int)(blockIdx.x * 4 + (threadIdx.x >> 6)));
    const int niter = (pw0 < NUNITS - 21 * STRIDE_UNITS) ? 22 : 21;

    for (int i = 0; i < niter; ++i) {
        const int p  = pw0 + i * STRIDE_UNITS;  // unit id, wave-uniform
        const int k  = p / UNITS_PER_ROW;       // output row (SALU magic-div)
        const int c  = p - k * UNITS_PER_ROW;   // 256-col chunk within the row
        const int g  = g_idx[k];                // group id (scalar load, sorted g_idx)
        const int kp = k >> 3;                  // qweight packed row
        const int sh = (k & 7) * 4;             // nibble of this row within the word

        const int n = c * 256 + lane4;          // absolute column of lane's 4 outputs

        // packed weights for 4 columns of row k (L2/L3-hot on rows 1..7 of a pack)
        const iv4 q = *reinterpret_cast<const iv4*>(&qweight[kp * NN + n]);
        const fv4 s = *reinterpret_cast<const fv4*>(&scales[g * NN + n]);
        const int zq = qzeros[g * NPACK + (n >> 3)] >> ((n & 4) * 4);

        fv4 o;
        o.x = fmaf(s.x, (float)((q.x >> sh) & 15), -s.x * (float)((zq      ) & 15));
        o.y = fmaf(s.y, (float)((q.y >> sh) & 15), -s.y * (float)((zq >>  4) & 15));
        o.z = fmaf(s.z, (float)((q.z >> sh) & 15), -s.z * (float)((zq >>  8) & 15));
        o.w = fmaf(s.w, (float)((q.w >> sh) & 15), -s.w * (float)((zq >> 12) & 15));

        // contiguous 1 KB store per wave at linear offset p*1KB:
        // k*NN + n == p*256 + lane4 (exact, since n = (p%43)*256 + lane4)
        *reinterpret_cast<fv4*>(out + (size_t)p * 256 + lane4) = o;
    }
}

extern "C" void kernel_launch(void* const* d_in, const int* in_sizes, int n_in,
                              void* d_out, int out_size, void* d_ws, size_t ws_size,
                              hipStream_t stream) {
    const int*   qweight = (const int*)d_in[0];
    const int*   qzeros  = (const int*)d_in[1];
    const float* scales  = (const float*)d_in[2];
    const int*   g_idx   = (const int*)d_in[3];
    float*       out     = (float*)d_out;

    dim3 block(256);
    dim3 grid(NBLOCKS);   // 2048 blocks = 8 resident blocks/CU, grid-striding units
    dequant_kernel<<<grid, block, 0, stream>>>(qweight, qzeros, scales, g_idx, out);
}

// Round 3
// 204.966 us; speedup vs baseline: 1.1038x; 1.1038x over previous
//
#include <hip/hip_runtime.h>

// DeQuantizer: 4-bit GPTQ-style weight dequantization.
// qweight: int32 [K/8, N], qzeros: int32 [G, N/8], scales: f32 [G, N],
// g_idx: int32 [K] (sorted). out: f32 [K, N].
// out[k][n] = scales[g][n] * (((qw[k/8][n] >> 4*(k%8)) & 15) - ((qz[g][n/8] >> 4*(n%8)) & 15))
// with g = g_idx[k].
//
// Round-3 theory: R1 (one load -> 8 row stores) was the best structure; its
// ~2.3 TB/s write phase is throttled by plain stores ALLOCATING dirty lines in
// the 4 MiB per-XCD L2 (the fill that hits 6.6 TB/s streams non-temporally).
// Output is never re-read, so L2 allocation of output lines is pure cost.
// Changes vs R1:
//   1. __builtin_nontemporal_store for ALL output stores (the lever).
//   2. 4 k-packs per block: 4 independent NT qweight loads up-front, then a
//      32-store train per thread; amortizes g_idx scalar loads and block
//      launch/drain. __launch_bounds__(256,4) leaves VGPR headroom (no spill).
// Kept from R1: qweight read exactly once (R2 proved re-reads cost full HBM),
// contiguous 1 KB per wave-store, ragged tail only in chunk 10.

#define NN 11008
#define NPACK (NN / 8)   // 1376
#define KPACKS 512       // 4096 / 8
#define KPB 4            // k-packs per block
#define NCHUNKS 11       // ceil(11008 / 1024)

typedef int   iv4 __attribute__((ext_vector_type(4)));
typedef float fv4 __attribute__((ext_vector_type(4)));

__global__ __launch_bounds__(256, 4) void dequant_kernel(
    const int* __restrict__ qweight,   // [512, N]
    const int* __restrict__ qzeros,    // [32, 1376]
    const float* __restrict__ scales,  // [32, N]
    const int* __restrict__ g_idx,     // [K]
    float* __restrict__ out)           // [K, N]
{
    const int kp0 = blockIdx.y * KPB;                    // first k-pack of this block
    const int n   = blockIdx.x * 1024 + threadIdx.x * 4; // 4 columns per thread
    if (n >= NN) return;                                 // only ragged in chunk 10

    // 4 independent packed-weight loads issued back-to-back (each word read
    // exactly once globally; NT: no reuse by anyone after this block)
    iv4 q[KPB];
    #pragma unroll
    for (int t = 0; t < KPB; ++t)
        q[t] = __builtin_nontemporal_load(
                   reinterpret_cast<const iv4*>(&qweight[(size_t)(kp0 + t) * NN + n]));

    const int zsh = (n & 4) * 4;    // cols n..n+3 -> nibbles of the zero word
    const int zw  = n >> 3;

    #pragma unroll
    for (int t = 0; t < KPB; ++t) {
        const int kp = kp0 + t;
        // group ids for this pack's 8 rows (block-uniform -> scalar loads)
        int gs[8];
        #pragma unroll
        for (int j = 0; j < 8; ++j) gs[j] = g_idx[kp * 8 + j];
        const int g0 = gs[0];
        // g_idx is sorted, so g0==g7 implies all 8 rows share one group (~94%)
        const bool uniform = (g0 == gs[7]);

        float* outp = &out[(size_t)(kp * 8) * NN + n];
        const iv4 q_ = q[t];

        if (uniform) {
            const int zq = qzeros[g0 * NPACK + zw] >> zsh;
            const fv4 s  = *reinterpret_cast<const fv4*>(&scales[g0 * NN + n]);
            const float cx = -s.x * (float)((zq      ) & 15);
            const float cy = -s.y * (float)((zq >>  4) & 15);
            const float cz = -s.z * (float)((zq >>  8) & 15);
            const float cw = -s.w * (float)((zq >> 12) & 15);

            #pragma unroll
            for (int j = 0; j < 8; ++j) {
                const int sh = 4 * j;
                fv4 o;
                o.x = fmaf(s.x, (float)((q_.x >> sh) & 15), cx);
                o.y = fmaf(s.y, (float)((q_.y >> sh) & 15), cy);
                o.z = fmaf(s.z, (float)((q_.z >> sh) & 15), cz);
                o.w = fmaf(s.w, (float)((q_.w >> sh) & 15), cw);
                __builtin_nontemporal_store(
                    o, reinterpret_cast<fv4*>(outp + (size_t)j * NN));
            }
        } else {
            #pragma unroll
            for (int j = 0; j < 8; ++j) {
                const int g  = gs[j];
                const int zq = qzeros[g * NPACK + zw] >> zsh;
                const fv4 s  = *reinterpret_cast<const fv4*>(&scales[g * NN + n]);
                const int sh = 4 * j;
                fv4 o;
                o.x = s.x * ((float)((q_.x >> sh) & 15) - (float)((zq      ) & 15));
                o.y = s.y * ((float)((q_.y >> sh) & 15) - (float)((zq >>  4) & 15));
                o.z = s.z * ((float)((q_.z >> sh) & 15) - (float)((zq >>  8) & 15));
                o.w = s.w * ((float)((q_.w >> sh) & 15) - (float)((zq >> 12) & 15));
                __builtin_nontemporal_store(
                    o, reinterpret_cast<fv4*>(outp + (size_t)j * NN));
            }
        }
    }
}

extern "C" void kernel_launch(void* const* d_in, const int* in_sizes, int n_in,
                              void* d_out, int out_size, void* d_ws, size_t ws_size,
                              hipStream_t stream) {
    const int*   qweight = (const int*)d_in[0];
    const int*   qzeros  = (const int*)d_in[1];
    const float* scales  = (const float*)d_in[2];
    const int*   g_idx   = (const int*)d_in[3];
    float*       out     = (float*)d_out;

    dim3 block(256);
    dim3 grid(NCHUNKS, KPACKS / KPB);   // (11, 128) = 1408 blocks
    dequant_kernel<<<grid, block, 0, stream>>>(qweight, qzeros, scales, g_idx, out);
}

// Round 4
// 197.023 us; speedup vs baseline: 1.1483x; 1.0403x over previous
//
#include <hip/hip_runtime.h>

// DeQuantizer: 4-bit GPTQ-style weight dequantization.
// qweight: int32 [K/8, N], qzeros: int32 [G, N/8], scales: f32 [G, N],
// g_idx: int32 [K] (sorted). out: f32 [K, N].
// out[k][n] = scales[g][n] * (((qw[k/8][n] >> 4*(k%8)) & 15) - ((qz[g][n/8] >> 4*(n%8)) & 15))
// with g = g_idx[k].
//
// Round-4: exact R1 structure (the session best: flat one-unit-per-block,
// 1 load -> 8 row stores, plain stores) with ONE change: the qweight load is
// PLAIN (cacheable) instead of nontemporal. Theory: NT loads bypass L2/L3, so
// each wave's 8-store train depends on a full-HBM-latency read whose QoS under
// 180 MB of concurrent write pressure is poor; plain loads ride the normal
// cache path. This is the last untested cell of the {order, NT-store, NT-load,
// depth, lifetime} matrix -- if it's flat, the ~2.3 TB/s write-phase cap is
// path-independent and R1 is within ~6% of the structural floor.

#define NN 11008
#define NPACK (NN / 8)   // 1376
#define KPACKS 512       // 4096 / 8
#define NCHUNKS 11       // ceil(11008 / 1024)

typedef int   iv4 __attribute__((ext_vector_type(4)));
typedef float fv4 __attribute__((ext_vector_type(4)));

__global__ __launch_bounds__(256, 8) void dequant_kernel(
    const int* __restrict__ qweight,   // [512, N]
    const int* __restrict__ qzeros,    // [32, 1376]
    const float* __restrict__ scales,  // [32, N]
    const int* __restrict__ g_idx,     // [K]
    float* __restrict__ out)           // [K, N]
{
    const int kp = blockIdx.y;                      // rows kp*8 .. kp*8+7
    const int n  = blockIdx.x * 1024 + threadIdx.x * 4;  // 4 columns per thread
    if (n >= NN) return;                            // only ragged in chunk 10

    // packed weights for this thread's 4 columns -- PLAIN load (the A/B lever):
    // read once globally, but let it use the normal L2/L3 path & QoS.
    const iv4 q = *reinterpret_cast<const iv4*>(&qweight[(size_t)kp * NN + n]);

    // group ids for this pack's 8 rows (block-uniform -> scalar loads)
    int gs[8];
    #pragma unroll
    for (int j = 0; j < 8; ++j) gs[j] = g_idx[kp * 8 + j];
    const int g0 = gs[0];
    // g_idx is sorted, so g0==g7 implies all 8 rows share one group (~94%)
    const bool uniform = (g0 == gs[7]);

    float* outp = &out[(size_t)(kp * 8) * NN + n];
    const int zsh = (n & 4) * 4;    // cols n..n+3 -> nibbles of the zero word
    const int zw  = n >> 3;

    if (uniform) {
        const int zq = qzeros[g0 * NPACK + zw] >> zsh;
        const fv4 s  = *reinterpret_cast<const fv4*>(&scales[g0 * NN + n]);
        const float cx = -s.x * (float)((zq      ) & 15);
        const float cy = -s.y * (float)((zq >>  4) & 15);
        const float cz = -s.z * (float)((zq >>  8) & 15);
        const float cw = -s.w * (float)((zq >> 12) & 15);

        #pragma unroll
        for (int j = 0; j < 8; ++j) {
            const int sh = 4 * j;
            fv4 o;
            o.x = fmaf(s.x, (float)((q.x >> sh) & 15), cx);
            o.y = fmaf(s.y, (float)((q.y >> sh) & 15), cy);
            o.z = fmaf(s.z, (float)((q.z >> sh) & 15), cz);
            o.w = fmaf(s.w, (float)((q.w >> sh) & 15), cw);
            *reinterpret_cast<fv4*>(outp + (size_t)j * NN) = o;
        }
    } else {
        #pragma unroll
        for (int j = 0; j < 8; ++j) {
            const int g  = gs[j];
            const int zq = qzeros[g * NPACK + zw] >> zsh;
            const fv4 s  = *reinterpret_cast<const fv4*>(&scales[g * NN + n]);
            const int sh = 4 * j;
            fv4 o;
            o.x = s.x * ((float)((q.x >> sh) & 15) - (float)((zq      ) & 15));
            o.y = s.y * ((float)((q.y >> sh) & 15) - (float)((zq >>  4) & 15));
            o.z = s.z * ((float)((q.z >> sh) & 15) - (float)((zq >>  8) & 15));
            o.w = s.w * ((float)((q.w >> sh) & 15) - (float)((zq >> 12) & 15));
            *reinterpret_cast<fv4*>(outp + (size_t)j * NN) = o;
        }
    }
}

extern "C" void kernel_launch(void* const* d_in, const int* in_sizes, int n_in,
                              void* d_out, int out_size, void* d_ws, size_t ws_size,
                              hipStream_t stream) {
    const int*   qweight = (const int*)d_in[0];
    const int*   qzeros  = (const int*)d_in[1];
    const float* scales  = (const float*)d_in[2];
    const int*   g_idx   = (const int*)d_in[3];
    float*       out     = (float*)d_out;

    dim3 block(256);
    dim3 grid(NCHUNKS, KPACKS);   // (11, 512) = 5632 blocks, 8 resident blocks/CU
    dequant_kernel<<<grid, block, 0, stream>>>(qweight, qzeros, scales, g_idx, out);
}